// Round 7
// baseline (1243.762 us; speedup 1.0000x reference)
//
#include <hip/hip_runtime.h>
#include <cstdint>
#include <cstddef>

// ---- problem constants ----
constexpr int Bn     = 512;
constexpr int Dd     = 11;
constexpr int LEAVES = 1024;
constexpr int NINT   = 1023;
constexpr int FLEAF  = 64;
constexpr int FINT   = 32;
constexpr int Hh     = 128;
constexpr int OUTC   = 33;

#define THREADS  256                  // prep kernel
#define WTHREADS 128                  // worker kernels: 32-row blocks, 2 waves
constexpr int KSTR  = 136;            // LDS/weight k-stride (u16): 272B rows, 16B aligned
constexpr int MATSZ = 128 * KSTR;     // u16 per half-matrix (hi or lo)

using short8 = __attribute__((ext_vector_type(8))) short;
using f32x4  = __attribute__((ext_vector_type(4))) float;

__device__ __forceinline__ unsigned int f2bf_rne_u(float f) {
  unsigned int u = __float_as_uint(f);
  u += 0x7fffu + ((u >> 16) & 1);
  return u;                            // bf16 in hi16
}
__device__ __forceinline__ unsigned short f2bf_rne(float f) {
  return (unsigned short)(f2bf_rne_u(f) >> 16);
}
__device__ __forceinline__ float bf2f(unsigned short h) {
  return __uint_as_float((unsigned int)h << 16);
}
__device__ __forceinline__ float trunc_bf(float a) {
  return __uint_as_float(__float_as_uint(a) & 0xffff0000u);
}
// hi16(a) -> lo16, hi16(b) -> hi16 : single v_perm_b32 byte-select
__device__ __forceinline__ unsigned int pack_hi_trunc(float a, float b) {
  return __builtin_amdgcn_perm(__float_as_uint(b), __float_as_uint(a), 0x07060302u);
}
// RNE-bf16 of a -> lo16, RNE-bf16 of b -> hi16 (HW packed convert, 1 instr)
__device__ __forceinline__ unsigned int pack_lo_rne(float a, float b) {
  unsigned int r;
  asm("v_cvt_pk_bf16_f32 %0, %1, %2" : "=v"(r) : "v"(a), "v"(b));
  return r;
}

// Swapped-operand dense layer: D = W_tile x Act^T, 32 rows/block, 2 waves.
// Wave w covers n-slice [w*64, w*64+64) as 4 n-tiles (NT=4), MT=2 row tiles.
// CONVOY-BREAKER design: 8 blocks/CU (LDS 17.4KB each), 2-wave barriers ->
// 8 independent barrier domains per CU (vs 4 before) for phase diversity.
// W loaded per-nt-PAIR inside the kc loop: live W = 4 short8 = 16 regs; acc 32;
// est ~100 arch VGPR < 128 cap (rounds 1-2: the 128-reg cliff is real).
template <int KC>
__device__ __forceinline__ void dense_layer(
    unsigned short* Ah, unsigned short* Al,
    const unsigned short* __restrict__ WTh, const unsigned short* __restrict__ WTl,
    const float* __restrict__ bias)
{
  const int tid  = threadIdx.x;
  const int wave = tid >> 6;          // 0..1
  const int lane = tid & 63;
  const int quad = lane >> 4;
  const int l16  = lane & 15;
  const int nbase = wave * 64;

  f32x4 c[2][4];                      // [mt][nt]
#pragma unroll
  for (int mt = 0; mt < 2; ++mt)
#pragma unroll
    for (int nt = 0; nt < 4; ++nt) c[mt][nt] = (f32x4){0.f, 0.f, 0.f, 0.f};

#pragma unroll
  for (int kc = 0; kc < KC; ++kc) {
    const int k0 = kc * 32 + quad * 8;
    short8 ah[2], al[2];
#pragma unroll
    for (int mt = 0; mt < 2; ++mt) {
      ah[mt] = *(const short8*)&Ah[(mt * 16 + l16) * KSTR + k0];
      al[mt] = *(const short8*)&Al[(mt * 16 + l16) * KSTR + k0];
    }
#pragma unroll
    for (int np = 0; np < 2; ++np) {  // nt pairs: {0,1}, {2,3}
      short8 wh[2], wl[2];
#pragma unroll
      for (int j = 0; j < 2; ++j) {
        const int n = nbase + (np * 2 + j) * 16 + l16;
        wh[j] = *(const short8*)&WTh[n * KSTR + k0];
        wl[j] = *(const short8*)&WTl[n * KSTR + k0];
      }
      // 3 term-groups x (mt2 x j2) = 12 MFMA; 4 acc chains, dep gap 4
#pragma unroll
      for (int mt = 0; mt < 2; ++mt)
#pragma unroll
        for (int j = 0; j < 2; ++j)
          c[mt][np * 2 + j] = __builtin_amdgcn_mfma_f32_16x16x32_bf16(wh[j], ah[mt], c[mt][np * 2 + j], 0, 0, 0);
#pragma unroll
      for (int mt = 0; mt < 2; ++mt)
#pragma unroll
        for (int j = 0; j < 2; ++j)
          c[mt][np * 2 + j] = __builtin_amdgcn_mfma_f32_16x16x32_bf16(wh[j], al[mt], c[mt][np * 2 + j], 0, 0, 0);
#pragma unroll
      for (int mt = 0; mt < 2; ++mt)
#pragma unroll
        for (int j = 0; j < 2; ++j)
          c[mt][np * 2 + j] = __builtin_amdgcn_mfma_f32_16x16x32_bf16(wl[j], ah[mt], c[mt][np * 2 + j], 0, 0, 0);
    }
  }
  __syncthreads();  // all reads of Ah/Al done before in-place overwrite

  float4 bv[4];
#pragma unroll
  for (int nt = 0; nt < 4; ++nt)
    bv[nt] = *(const float4*)&bias[nbase + nt * 16 + quad * 4];

#pragma unroll
  for (int mt = 0; mt < 2; ++mt) {
    const int m = mt * 16 + l16;
#pragma unroll
    for (int nt = 0; nt < 4; ++nt) {
      const int nb = nbase + nt * 16 + quad * 4;
      float v0 = fmaxf(c[mt][nt][0] + bv[nt].x, 0.f);
      float v1 = fmaxf(c[mt][nt][1] + bv[nt].y, 0.f);
      float v2 = fmaxf(c[mt][nt][2] + bv[nt].z, 0.f);
      float v3 = fmaxf(c[mt][nt][3] + bv[nt].w, 0.f);
      const unsigned int h0 = pack_hi_trunc(v0, v1);
      const unsigned int h1 = pack_hi_trunc(v2, v3);
      const unsigned int l0 = pack_lo_rne(v0 - trunc_bf(v0), v1 - trunc_bf(v1));
      const unsigned int l1 = pack_lo_rne(v2 - trunc_bf(v2), v3 - trunc_bf(v3));
      *(uint2*)&Ah[m * KSTR + nb] = make_uint2(h0, h1);
      *(uint2*)&Al[m * KSTR + nb] = make_uint2(l0, l1);
    }
  }
  __syncthreads();
}

// Output layer: [32 x 128] @ [128 x 33] + bias (linear). 48 padded cols as 3 n-tiles:
// wave 0 -> tiles 0,1; wave 1 -> tile 2. Writes u16 hi/lo rows (stride 33);
// if finalOut != nullptr (n==1 level), writes per-row fp32 scalar (n==0 column).
__device__ __forceinline__ void out_layer(
    const unsigned short* Ah, const unsigned short* Al,
    const unsigned short* __restrict__ WTh, const unsigned short* __restrict__ WTl,
    const float* __restrict__ bias,
    unsigned short* outH, unsigned short* outL, float* finalOut)
{
  const int tid  = threadIdx.x;
  const int wave = tid >> 6;
  const int lane = tid & 63;
  const int quad = lane >> 4;
  const int l16  = lane & 15;
#pragma unroll
  for (int t = 0; t < 2; ++t) {
    const int tile = wave * 2 + t;
    if (tile < 3) {
      const int n_row = tile * 16 + l16;
      f32x4 c[2];
#pragma unroll
      for (int mt = 0; mt < 2; ++mt) c[mt] = (f32x4){0.f, 0.f, 0.f, 0.f};
#pragma unroll
      for (int kc = 0; kc < 4; ++kc) {
        const int k0 = kc * 32 + quad * 8;
        const short8 wh = *(const short8*)&WTh[n_row * KSTR + k0];
        const short8 wl = *(const short8*)&WTl[n_row * KSTR + k0];
        short8 ah[2], al[2];
#pragma unroll
        for (int mt = 0; mt < 2; ++mt) {
          ah[mt] = *(const short8*)&Ah[(mt * 16 + l16) * KSTR + k0];
          al[mt] = *(const short8*)&Al[(mt * 16 + l16) * KSTR + k0];
        }
#pragma unroll
        for (int mt = 0; mt < 2; ++mt)
          c[mt] = __builtin_amdgcn_mfma_f32_16x16x32_bf16(wh, ah[mt], c[mt], 0, 0, 0);
#pragma unroll
        for (int mt = 0; mt < 2; ++mt)
          c[mt] = __builtin_amdgcn_mfma_f32_16x16x32_bf16(wh, al[mt], c[mt], 0, 0, 0);
#pragma unroll
        for (int mt = 0; mt < 2; ++mt)
          c[mt] = __builtin_amdgcn_mfma_f32_16x16x32_bf16(wl, ah[mt], c[mt], 0, 0, 0);
      }
      const int nb = tile * 16 + quad * 4;
      const float4 bv = *(const float4*)&bias[nb];
      const float bvr[4] = {bv.x, bv.y, bv.z, bv.w};
#pragma unroll
      for (int mt = 0; mt < 2; ++mt) {
        const int m = mt * 16 + l16;
#pragma unroll
        for (int r = 0; r < 4; ++r) {
          const int n = nb + r;
          const float v = c[mt][r] + bvr[r];
          if (n < OUTC) {
            outH[m * 33 + n] = (unsigned short)(__float_as_uint(v) >> 16);
            outL[m * 33 + n] = f2bf_rne(v - trunc_bf(v));
          }
          if (finalOut && n == 0) finalOut[m] = v;
        }
      }
    }
  }
}

__global__ __launch_bounds__(WTHREADS, 4)   // 4 waves/EU -> 8 blocks/CU (128-reg cap)
void leaf_kernel(const float* __restrict__ X,
                 const unsigned short* __restrict__ warena,
                 const float* __restrict__ barena,
                 unsigned short* __restrict__ outH, unsigned short* __restrict__ outL)
{
  __shared__ unsigned short Ah[32 * KSTR];
  __shared__ unsigned short Al[32 * KSTR];
  const int row_base = blockIdx.x * 32;
  const int tid = threadIdx.x;

#pragma unroll
  for (int j = 0; j < 4; ++j) {
    const int e  = tid + j * WTHREADS;                 // 0..511
    const int r  = e >> 4;                             // 0..31
    const int k0 = (e & 15) << 2;
    const float4 v = *(const float4*)&X[(size_t)(row_base + r) * FLEAF + k0];
    const unsigned int h0 = pack_hi_trunc(v.x, v.y);
    const unsigned int h1 = pack_hi_trunc(v.z, v.w);
    const unsigned int l0 = pack_lo_rne(v.x - trunc_bf(v.x), v.y - trunc_bf(v.y));
    const unsigned int l1 = pack_lo_rne(v.z - trunc_bf(v.z), v.w - trunc_bf(v.w));
    *(uint2*)&Ah[r * KSTR + k0] = make_uint2(h0, h1);
    *(uint2*)&Al[r * KSTR + k0] = make_uint2(l0, l1);
  }
  __syncthreads();

  dense_layer<2>(Ah, Al, warena + 0 * 2 * MATSZ, warena + 0 * 2 * MATSZ + MATSZ, barena + 0 * 128);
#pragma unroll
  for (int l = 0; l < 4; ++l) {
    const int id = 1 + l;
    dense_layer<4>(Ah, Al, warena + id * 2 * MATSZ, warena + id * 2 * MATSZ + MATSZ, barena + id * 128);
  }
  out_layer(Ah, Al, warena + 5 * 2 * MATSZ, warena + 5 * 2 * MATSZ + MATSZ, barena + 5 * 128,
            outH + (size_t)row_base * 33, outL + (size_t)row_base * 33, nullptr);
}

// One tree level, batched across ALL batches: rows = Bn * n, 32 rows/block, every row
// real work. Per-row staging: valid for any n >= 1 (b derived per row; min level
// d0 has Bn = 512 rows = 16 full blocks). If finalOut != nullptr: per-row fp32 scalar.
__global__ __launch_bounds__(WTHREADS, 4)
void int_kernel(const float* __restrict__ feat,
                const unsigned short* __restrict__ prevH, const unsigned short* __restrict__ prevL,
                const unsigned short* __restrict__ warena, const float* __restrict__ barena,
                unsigned short* __restrict__ outH, unsigned short* __restrict__ outL,
                float* __restrict__ finalOut,
                int n, int logn)
{
  __shared__ unsigned short Ah[32 * KSTR];
  __shared__ unsigned short Al[32 * KSTR];
  const int tid = threadIdx.x;
  const int m = tid & 31;
  const int g = tid >> 5;                              // 0..3
  const int row = blockIdx.x * 32 + m;
  const int b = row >> logn;
  const int i = row & (n - 1);

  // feat: 32 fp32 -> 16 float2 chunks, convert + packed u32 LDS writes
  const float* fr = feat + ((size_t)b * NINT + (n - 1) + i) * FINT;
#pragma unroll
  for (int j = 0; j < 4; ++j) {
    const int cch = g + 4 * j;                         // 0..15
    const float2 v = *(const float2*)&fr[cch * 2];
    *(unsigned int*)&Ah[m * KSTR + cch * 2] = pack_hi_trunc(v.x, v.y);
    *(unsigned int*)&Al[m * KSTR + cch * 2] = pack_lo_rne(v.x - trunc_bf(v.x), v.y - trunc_bf(v.y));
  }
  // children: rows 2i,2i+1 are 66 contiguous u16 in prev (c0 always even -> u32 copies)
  const size_t c0 = ((size_t)b * (n << 1) + (i << 1)) * 33;
#pragma unroll
  for (int j = 0; j < 9; ++j) {
    const int p = g + 4 * j;                           // 0..35
    if (p < 33) {
      const unsigned int hv = *(const unsigned int*)&prevH[c0 + 2 * p];
      const unsigned int lv = *(const unsigned int*)&prevL[c0 + 2 * p];
      *(unsigned int*)&Ah[m * KSTR + 32 + 2 * p] = hv;
      *(unsigned int*)&Al[m * KSTR + 32 + 2 * p] = lv;
    }
  }
  // zero-pad k = 98..127
#pragma unroll
  for (int j = 0; j < 4; ++j) {
    const int p = g + 4 * j;                           // 0..15
    if (p < 15) {
      *(unsigned int*)&Ah[m * KSTR + 98 + 2 * p] = 0u;
      *(unsigned int*)&Al[m * KSTR + 98 + 2 * p] = 0u;
    }
  }
  __syncthreads();

  dense_layer<4>(Ah, Al, warena + 6 * 2 * MATSZ, warena + 6 * 2 * MATSZ + MATSZ, barena + 6 * 128);
#pragma unroll
  for (int l = 0; l < 4; ++l) {
    const int id = 7 + l;
    dense_layer<4>(Ah, Al, warena + id * 2 * MATSZ, warena + id * 2 * MATSZ + MATSZ, barena + id * 128);
  }
  out_layer(Ah, Al, warena + 11 * 2 * MATSZ, warena + 11 * 2 * MATSZ + MATSZ, barena + 11 * 128,
            outH + (size_t)blockIdx.x * 32 * 33, outL + (size_t)blockIdx.x * 32 * 33,
            finalOut ? (finalOut + blockIdx.x * 32) : nullptr);
}

// Pre-transpose + hi/lo split 12 weight matrices into WT[n][KSTR] (RNE both halves),
// pack biases zero-padded to 128.
__global__ void prep_kernel(const float* __restrict__ lW_in, const float* __restrict__ lW_hid,
                            const float* __restrict__ lW_out, const float* __restrict__ lb_in,
                            const float* __restrict__ lb_hid, const float* __restrict__ lb_out,
                            const float* __restrict__ iW_in, const float* __restrict__ iW_hid,
                            const float* __restrict__ iW_out, const float* __restrict__ ib_in,
                            const float* __restrict__ ib_hid, const float* __restrict__ ib_out,
                            unsigned short* __restrict__ warena, float* __restrict__ barena)
{
  const int id = blockIdx.y;
  const float* W; const float* bs; int K, N;
  if (id == 0)       { W = lW_in;                        bs = lb_in;                 K = FLEAF; N = Hh; }
  else if (id <= 4)  { W = lW_hid + (id - 1) * Hh * Hh;  bs = lb_hid + (id - 1) * Hh; K = Hh;   N = Hh; }
  else if (id == 5)  { W = lW_out;                       bs = lb_out;                K = Hh;    N = OUTC; }
  else if (id == 6)  { W = iW_in;                        bs = ib_in;                 K = FINT + 2 * OUTC; N = Hh; }
  else if (id <= 10) { W = iW_hid + (id - 7) * Hh * Hh;  bs = ib_hid + (id - 7) * Hh; K = Hh;   N = Hh; }
  else               { W = iW_out;                       bs = ib_out;                K = Hh;    N = OUTC; }

  unsigned short* dh = warena + id * 2 * MATSZ;
  unsigned short* dl = dh + MATSZ;
  const int e = blockIdx.x * THREADS + threadIdx.x;
  if (e < MATSZ) {
    const int nn = e / KSTR;
    const int kk = e - nn * KSTR;
    const float v = (kk < K && nn < N) ? W[(size_t)kk * N + nn] : 0.f;
    const unsigned short h = f2bf_rne(v);
    dh[e] = h;
    dl[e] = f2bf_rne(v - bf2f(h));
  }
  if (blockIdx.x == 0 && threadIdx.x < 128)
    barena[id * 128 + threadIdx.x] = (threadIdx.x < N) ? bs[threadIdx.x] : 0.f;
}

extern "C" void kernel_launch(void* const* d_in, const int* in_sizes, int n_in,
                              void* d_out, int out_size, void* d_ws, size_t ws_size,
                              hipStream_t stream) {
  const float* leaf_feat = (const float*)d_in[0];
  const float* int_feat  = (const float*)d_in[1];
  const float* lW_in  = (const float*)d_in[2];
  const float* lb_in  = (const float*)d_in[3];
  const float* lW_hid = (const float*)d_in[4];
  const float* lb_hid = (const float*)d_in[5];
  const float* lW_out = (const float*)d_in[6];
  const float* lb_out = (const float*)d_in[7];
  const float* iW_in  = (const float*)d_in[8];
  const float* ib_in  = (const float*)d_in[9];
  const float* iW_hid = (const float*)d_in[10];
  const float* ib_hid = (const float*)d_in[11];
  const float* iW_out = (const float*)d_in[12];
  const float* ib_out = (const float*)d_in[13];
  float* out = (float*)d_out;

  // ws layout (u16 hi/lo stage buffers, stride 33):
  //  A: 524288 rows, B: 262144 rows; levels ping-pong A<->B.
  const size_t rowsA = (size_t)Bn * LEAVES;       // 524288
  const size_t rowsB = rowsA / 2;                 // 262144
  unsigned short* AH = (unsigned short*)d_ws;
  unsigned short* AL = AH + rowsA * 33;
  unsigned short* BH = AL + rowsA * 33;
  unsigned short* BL = BH + rowsB * 33;
  unsigned short* warena = BL + rowsB * 33;
  float* barena = (float*)(warena + 24 * MATSZ);  // total ~104.7 MB

  prep_kernel<<<dim3((MATSZ + THREADS - 1) / THREADS, 12), THREADS, 0, stream>>>(
      lW_in, lW_hid, lW_out, lb_in, lb_hid, lb_out,
      iW_in, iW_hid, iW_out, ib_in, ib_hid, ib_out, warena, barena);

  leaf_kernel<<<(Bn * LEAVES) / 32, WTHREADS, 0, stream>>>(leaf_feat, warena, barena, AH, AL);

  // All 10 interior levels batched across batches; 32 real rows per block.
  // d:     9     8     7     6     5    4    3    2   1   0
  // grid: 8192  4096  2048  1024  512  256  128  64  32  16
  int_kernel<<<8192, WTHREADS, 0, stream>>>(int_feat, AH, AL, warena, barena, BH, BL, nullptr, 512, 9);
  int_kernel<<<4096, WTHREADS, 0, stream>>>(int_feat, BH, BL, warena, barena, AH, AL, nullptr, 256, 8);
  int_kernel<<<2048, WTHREADS, 0, stream>>>(int_feat, AH, AL, warena, barena, BH, BL, nullptr, 128, 7);
  int_kernel<<<1024, WTHREADS, 0, stream>>>(int_feat, BH, BL, warena, barena, AH, AL, nullptr,  64, 6);
  int_kernel<<< 512, WTHREADS, 0, stream>>>(int_feat, AH, AL, warena, barena, BH, BL, nullptr,  32, 5);
  int_kernel<<< 256, WTHREADS, 0, stream>>>(int_feat, BH, BL, warena, barena, AH, AL, nullptr,  16, 4);
  int_kernel<<< 128, WTHREADS, 0, stream>>>(int_feat, AH, AL, warena, barena, BH, BL, nullptr,   8, 3);
  int_kernel<<<  64, WTHREADS, 0, stream>>>(int_feat, BH, BL, warena, barena, AH, AL, nullptr,   4, 2);
  int_kernel<<<  32, WTHREADS, 0, stream>>>(int_feat, AH, AL, warena, barena, BH, BL, nullptr,   2, 1);
  int_kernel<<<  16, WTHREADS, 0, stream>>>(int_feat, BH, BL, warena, barena, AH, AL, out,        1, 0);
}

// Round 8
// 832.708 us; speedup vs baseline: 1.4936x; 1.4936x over previous
//
#include <hip/hip_runtime.h>
#include <cstdint>
#include <cstddef>

// ---- problem constants ----
constexpr int Bn     = 512;
constexpr int Dd     = 11;
constexpr int LEAVES = 1024;
constexpr int NINT   = 1023;
constexpr int FLEAF  = 64;
constexpr int FINT   = 32;
constexpr int Hh     = 128;
constexpr int OUTC   = 33;

#define THREADS 256
constexpr int KSTR  = 136;            // LDS/weight k-stride (u16): 272B rows, 16B aligned
constexpr int MATSZ = 128 * KSTR;     // u16 per half-matrix (hi or lo)

using short8 = __attribute__((ext_vector_type(8))) short;
using f32x4  = __attribute__((ext_vector_type(4))) float;

__device__ __forceinline__ unsigned int f2bf_rne_u(float f) {
  unsigned int u = __float_as_uint(f);
  u += 0x7fffu + ((u >> 16) & 1);
  return u;                            // bf16 in hi16
}
__device__ __forceinline__ unsigned short f2bf_rne(float f) {
  return (unsigned short)(f2bf_rne_u(f) >> 16);
}
__device__ __forceinline__ float bf2f(unsigned short h) {
  return __uint_as_float((unsigned int)h << 16);
}
__device__ __forceinline__ float trunc_bf(float a) {
  return __uint_as_float(__float_as_uint(a) & 0xffff0000u);
}
// hi16(a) -> lo16, hi16(b) -> hi16 : single v_perm_b32 byte-select (bit-identical
// to shift/mask; verified passing rounds 6-7).
__device__ __forceinline__ unsigned int pack_hi_trunc(float a, float b) {
  return __builtin_amdgcn_perm(__float_as_uint(b), __float_as_uint(a), 0x07060302u);
}
// RNE-bf16 of a -> lo16, RNE-bf16 of b -> hi16 (HW packed convert, 1 instr)
__device__ __forceinline__ unsigned int pack_lo_rne(float a, float b) {
  unsigned int r;
  asm("v_cvt_pk_bf16_f32 %0, %1, %2" : "=v"(r) : "v"(a), "v"(b));
  return r;
}

// Swapped-operand dense layer: D = W_tile x Act^T.  Round-0/4 proven body
// (64 arch VGPR + 32 acc, under the 128-total / 4-blocks-per-CU cliff — rounds 1-2
// showed ANY added live loop state either drops a block or spills).
// Round-8 deltas: bias load after barrier (8 regs freed in loop); s_setprio(1)
// around the MFMA clusters (4 staggered blocks/CU = phase diversity regime).
template <int KC, int MT>
__device__ __forceinline__ void dense_layer(
    unsigned short* Ah, unsigned short* Al,
    const unsigned short* __restrict__ WTh, const unsigned short* __restrict__ WTl,
    const float* __restrict__ bias)
{
  const int tid  = threadIdx.x;
  const int wave = tid >> 6;
  const int lane = tid & 63;
  const int quad = lane >> 4;
  const int l16  = lane & 15;
  const int nbase = wave * 32;

  // preload W-hi fragments (8 frags = 32 VGPR for KC=4)
  short8 wh[2][KC];
#pragma unroll
  for (int nt = 0; nt < 2; ++nt) {
    const int n = nbase + nt * 16 + l16;
#pragma unroll
    for (int kc = 0; kc < KC; ++kc)
      wh[nt][kc] = *(const short8*)&WTh[n * KSTR + kc * 32 + quad * 8];
  }

  f32x4 c[MT][2];
#pragma unroll
  for (int mt = 0; mt < MT; ++mt)
#pragma unroll
    for (int nt = 0; nt < 2; ++nt) c[mt][nt] = (f32x4){0.f, 0.f, 0.f, 0.f};

#pragma unroll
  for (int kc = 0; kc < KC; ++kc) {
    const int k0 = kc * 32 + quad * 8;
    short8 wl[2];
#pragma unroll
    for (int nt = 0; nt < 2; ++nt) {
      const int n = nbase + nt * 16 + l16;
      wl[nt] = *(const short8*)&WTl[n * KSTR + k0];
    }
    short8 ah[MT], al[MT];
#pragma unroll
    for (int mt = 0; mt < MT; ++mt) {
      ah[mt] = *(const short8*)&Ah[(mt * 16 + l16) * KSTR + k0];
      al[mt] = *(const short8*)&Al[(mt * 16 + l16) * KSTR + k0];
    }
    __builtin_amdgcn_s_setprio(1);
    // grouped by term: consecutive MFMAs independent across tiles
#pragma unroll
    for (int mt = 0; mt < MT; ++mt)
#pragma unroll
      for (int nt = 0; nt < 2; ++nt)
        c[mt][nt] = __builtin_amdgcn_mfma_f32_16x16x32_bf16(wh[nt][kc], ah[mt], c[mt][nt], 0, 0, 0);
#pragma unroll
    for (int mt = 0; mt < MT; ++mt)
#pragma unroll
      for (int nt = 0; nt < 2; ++nt)
        c[mt][nt] = __builtin_amdgcn_mfma_f32_16x16x32_bf16(wh[nt][kc], al[mt], c[mt][nt], 0, 0, 0);
#pragma unroll
    for (int mt = 0; mt < MT; ++mt)
#pragma unroll
      for (int nt = 0; nt < 2; ++nt)
        c[mt][nt] = __builtin_amdgcn_mfma_f32_16x16x32_bf16(wl[nt], ah[mt], c[mt][nt], 0, 0, 0);
    __builtin_amdgcn_s_setprio(0);
  }
  __syncthreads();  // all reads of Ah/Al done before in-place overwrite

  // bias loaded here: loop registers are dead, pressure is low
  float4 bv[2];
#pragma unroll
  for (int nt = 0; nt < 2; ++nt)
    bv[nt] = *(const float4*)&bias[nbase + nt * 16 + quad * 4];

#pragma unroll
  for (int mt = 0; mt < MT; ++mt) {
    const int m = mt * 16 + l16;
#pragma unroll
    for (int nt = 0; nt < 2; ++nt) {
      const int nb = nbase + nt * 16 + quad * 4;
      float v0 = fmaxf(c[mt][nt][0] + bv[nt].x, 0.f);
      float v1 = fmaxf(c[mt][nt][1] + bv[nt].y, 0.f);
      float v2 = fmaxf(c[mt][nt][2] + bv[nt].z, 0.f);
      float v3 = fmaxf(c[mt][nt][3] + bv[nt].w, 0.f);
      const unsigned int h0 = pack_hi_trunc(v0, v1);
      const unsigned int h1 = pack_hi_trunc(v2, v3);
      const unsigned int l0 = pack_lo_rne(v0 - trunc_bf(v0), v1 - trunc_bf(v1));
      const unsigned int l1 = pack_lo_rne(v2 - trunc_bf(v2), v3 - trunc_bf(v3));
      *(uint2*)&Ah[m * KSTR + nb] = make_uint2(h0, h1);
      *(uint2*)&Al[m * KSTR + nb] = make_uint2(l0, l1);
    }
  }
  __syncthreads();
}

// Output layer: [M x 128] @ [128 x 33] + bias (linear). Writes u16 hi/lo rows (stride 33)
// to outH/outL; if finalOut != nullptr, writes per-row fp32 scalar (n==0 column).
template <int MT>
__device__ __forceinline__ void out_layer(
    const unsigned short* Ah, const unsigned short* Al,
    const unsigned short* __restrict__ WTh, const unsigned short* __restrict__ WTl,
    const float* __restrict__ bias,
    unsigned short* outH, unsigned short* outL, float* finalOut)
{
  const int tid  = threadIdx.x;
  const int wave = tid >> 6;
  const int lane = tid & 63;
  const int quad = lane >> 4;
  const int l16  = lane & 15;
  if (wave < 3) {                       // 48 padded cols cover 33
    const int n_row = wave * 16 + l16;
    short8 wh[4], wl[4];
#pragma unroll
    for (int kc = 0; kc < 4; ++kc) {
      wh[kc] = *(const short8*)&WTh[n_row * KSTR + kc * 32 + quad * 8];
      wl[kc] = *(const short8*)&WTl[n_row * KSTR + kc * 32 + quad * 8];
    }
    const int nb = wave * 16 + quad * 4;
    const float4 bv = *(const float4*)&bias[nb];
    const float bvr[4] = {bv.x, bv.y, bv.z, bv.w};

    f32x4 c[MT];
#pragma unroll
    for (int mt = 0; mt < MT; ++mt) c[mt] = (f32x4){0.f, 0.f, 0.f, 0.f};
#pragma unroll
    for (int kc = 0; kc < 4; ++kc) {
      const int k0 = kc * 32 + quad * 8;
      __builtin_amdgcn_s_setprio(1);
#pragma unroll
      for (int mt = 0; mt < MT; ++mt) {
        const short8 ah = *(const short8*)&Ah[(mt * 16 + l16) * KSTR + k0];
        const short8 al = *(const short8*)&Al[(mt * 16 + l16) * KSTR + k0];
        c[mt] = __builtin_amdgcn_mfma_f32_16x16x32_bf16(wh[kc], ah, c[mt], 0, 0, 0);
        c[mt] = __builtin_amdgcn_mfma_f32_16x16x32_bf16(wh[kc], al, c[mt], 0, 0, 0);
        c[mt] = __builtin_amdgcn_mfma_f32_16x16x32_bf16(wl[kc], ah, c[mt], 0, 0, 0);
      }
      __builtin_amdgcn_s_setprio(0);
    }
#pragma unroll
    for (int mt = 0; mt < MT; ++mt) {
      const int m = mt * 16 + l16;
#pragma unroll
      for (int r = 0; r < 4; ++r) {
        const int n = nb + r;
        const float v = c[mt][r] + bvr[r];
        if (n < OUTC) {
          outH[m * 33 + n] = (unsigned short)(__float_as_uint(v) >> 16);
          outL[m * 33 + n] = f2bf_rne(v - trunc_bf(v));
        }
        if (finalOut && n == 0) finalOut[m] = v;
      }
    }
  }
}

__global__ __launch_bounds__(THREADS, 4)
void leaf_kernel(const float* __restrict__ X,
                 const unsigned short* __restrict__ warena,
                 const float* __restrict__ barena,
                 unsigned short* __restrict__ outH, unsigned short* __restrict__ outL)
{
  __shared__ unsigned short Ah[64 * KSTR];
  __shared__ unsigned short Al[64 * KSTR];
  const int row_base = blockIdx.x * 64;
  const int tid = threadIdx.x;

  for (int e = tid; e < 64 * 16; e += THREADS) {
    const int r  = e >> 4;
    const int k0 = (e & 15) << 2;
    const float4 v = *(const float4*)&X[(size_t)(row_base + r) * FLEAF + k0];
    const unsigned int h0 = pack_hi_trunc(v.x, v.y);
    const unsigned int h1 = pack_hi_trunc(v.z, v.w);
    const unsigned int l0 = pack_lo_rne(v.x - trunc_bf(v.x), v.y - trunc_bf(v.y));
    const unsigned int l1 = pack_lo_rne(v.z - trunc_bf(v.z), v.w - trunc_bf(v.w));
    *(uint2*)&Ah[r * KSTR + k0] = make_uint2(h0, h1);
    *(uint2*)&Al[r * KSTR + k0] = make_uint2(l0, l1);
  }
  __syncthreads();

  dense_layer<2, 4>(Ah, Al, warena + 0 * 2 * MATSZ, warena + 0 * 2 * MATSZ + MATSZ, barena + 0 * 128);
#pragma unroll
  for (int l = 0; l < 4; ++l) {
    const int id = 1 + l;
    dense_layer<4, 4>(Ah, Al, warena + id * 2 * MATSZ, warena + id * 2 * MATSZ + MATSZ, barena + id * 128);
  }
  out_layer<4>(Ah, Al, warena + 5 * 2 * MATSZ, warena + 5 * 2 * MATSZ + MATSZ, barena + 5 * 128,
               outH + (size_t)row_base * 33, outL + (size_t)row_base * 33, nullptr);
}

// One tree level, batched across ALL batches: rows = Bn * n, 64 rows/block.
// Staging remap (round-8): 4 lanes per row (row = tid>>2, sub = tid&3):
//  - LDS writes: banks (4*row + word) -> 2-way (free) instead of 8-way
//  - global reads: 4 consecutive words per row instead of one 264B-strided lane/row
// Valid for any n >= 1 (b derived per row). If finalOut != nullptr: per-row fp32 scalar.
__global__ __launch_bounds__(THREADS, 4)
void int_kernel(const float* __restrict__ feat,
                const unsigned short* __restrict__ prevH, const unsigned short* __restrict__ prevL,
                const unsigned short* __restrict__ warena, const float* __restrict__ barena,
                unsigned short* __restrict__ outH, unsigned short* __restrict__ outL,
                float* __restrict__ finalOut,
                int n, int logn)
{
  __shared__ unsigned short Ah[64 * KSTR];
  __shared__ unsigned short Al[64 * KSTR];
  const int tid = threadIdx.x;
  const int m   = tid >> 2;                            // 0..63 (row)
  const int sub = tid & 3;                             // 0..3  (chunk lane)
  const int row = blockIdx.x * 64 + m;
  const int b = row >> logn;
  const int i = row & (n - 1);

  // feat: 32 fp32 -> 16 float2 chunks, convert + packed u32 LDS writes
  const float* fr = feat + ((size_t)b * NINT + (n - 1) + i) * FINT;
#pragma unroll
  for (int j = 0; j < 4; ++j) {
    const int cch = sub + 4 * j;                       // 0..15
    const float2 v = *(const float2*)&fr[cch * 2];
    *(unsigned int*)&Ah[m * KSTR + cch * 2] = pack_hi_trunc(v.x, v.y);
    *(unsigned int*)&Al[m * KSTR + cch * 2] = pack_lo_rne(v.x - trunc_bf(v.x), v.y - trunc_bf(v.y));
  }
  // children: rows 2i,2i+1 are 66 contiguous u16 in prev (c0 always even -> u32 copies)
  const size_t c0 = ((size_t)b * (n << 1) + (i << 1)) * 33;
#pragma unroll
  for (int j = 0; j < 9; ++j) {
    const int p = sub + 4 * j;                         // 0..35
    if (p < 33) {
      const unsigned int hv = *(const unsigned int*)&prevH[c0 + 2 * p];
      const unsigned int lv = *(const unsigned int*)&prevL[c0 + 2 * p];
      *(unsigned int*)&Ah[m * KSTR + 32 + 2 * p] = hv;
      *(unsigned int*)&Al[m * KSTR + 32 + 2 * p] = lv;
    }
  }
  // zero-pad k = 98..127
#pragma unroll
  for (int j = 0; j < 4; ++j) {
    const int p = sub + 4 * j;                         // 0..15
    if (p < 15) {
      *(unsigned int*)&Ah[m * KSTR + 98 + 2 * p] = 0u;
      *(unsigned int*)&Al[m * KSTR + 98 + 2 * p] = 0u;
    }
  }
  __syncthreads();

  dense_layer<4, 4>(Ah, Al, warena + 6 * 2 * MATSZ, warena + 6 * 2 * MATSZ + MATSZ, barena + 6 * 128);
#pragma unroll
  for (int l = 0; l < 4; ++l) {
    const int id = 7 + l;
    dense_layer<4, 4>(Ah, Al, warena + id * 2 * MATSZ, warena + id * 2 * MATSZ + MATSZ, barena + id * 128);
  }
  out_layer<4>(Ah, Al, warena + 11 * 2 * MATSZ, warena + 11 * 2 * MATSZ + MATSZ, barena + 11 * 128,
               outH + (size_t)blockIdx.x * 64 * 33, outL + (size_t)blockIdx.x * 64 * 33,
               finalOut ? (finalOut + blockIdx.x * 64) : nullptr);
}

// Pre-transpose + hi/lo split 12 weight matrices into WT[n][KSTR] (RNE both halves),
// pack biases zero-padded to 128.
__global__ void prep_kernel(const float* __restrict__ lW_in, const float* __restrict__ lW_hid,
                            const float* __restrict__ lW_out, const float* __restrict__ lb_in,
                            const float* __restrict__ lb_hid, const float* __restrict__ lb_out,
                            const float* __restrict__ iW_in, const float* __restrict__ iW_hid,
                            const float* __restrict__ iW_out, const float* __restrict__ ib_in,
                            const float* __restrict__ ib_hid, const float* __restrict__ ib_out,
                            unsigned short* __restrict__ warena, float* __restrict__ barena)
{
  const int id = blockIdx.y;
  const float* W; const float* bs; int K, N;
  if (id == 0)       { W = lW_in;                        bs = lb_in;                 K = FLEAF; N = Hh; }
  else if (id <= 4)  { W = lW_hid + (id - 1) * Hh * Hh;  bs = lb_hid + (id - 1) * Hh; K = Hh;   N = Hh; }
  else if (id == 5)  { W = lW_out;                       bs = lb_out;                K = Hh;    N = OUTC; }
  else if (id == 6)  { W = iW_in;                        bs = ib_in;                 K = FINT + 2 * OUTC; N = Hh; }
  else if (id <= 10) { W = iW_hid + (id - 7) * Hh * Hh;  bs = ib_hid + (id - 7) * Hh; K = Hh;   N = Hh; }
  else               { W = iW_out;                       bs = ib_out;                K = Hh;    N = OUTC; }

  unsigned short* dh = warena + id * 2 * MATSZ;
  unsigned short* dl = dh + MATSZ;
  const int e = blockIdx.x * THREADS + threadIdx.x;
  if (e < MATSZ) {
    const int nn = e / KSTR;
    const int kk = e - nn * KSTR;
    const float v = (kk < K && nn < N) ? W[(size_t)kk * N + nn] : 0.f;
    const unsigned short h = f2bf_rne(v);
    dh[e] = h;
    dl[e] = f2bf_rne(v - bf2f(h));
  }
  if (blockIdx.x == 0 && threadIdx.x < 128)
    barena[id * 128 + threadIdx.x] = (threadIdx.x < N) ? bs[threadIdx.x] : 0.f;
}

extern "C" void kernel_launch(void* const* d_in, const int* in_sizes, int n_in,
                              void* d_out, int out_size, void* d_ws, size_t ws_size,
                              hipStream_t stream) {
  const float* leaf_feat = (const float*)d_in[0];
  const float* int_feat  = (const float*)d_in[1];
  const float* lW_in  = (const float*)d_in[2];
  const float* lb_in  = (const float*)d_in[3];
  const float* lW_hid = (const float*)d_in[4];
  const float* lb_hid = (const float*)d_in[5];
  const float* lW_out = (const float*)d_in[6];
  const float* lb_out = (const float*)d_in[7];
  const float* iW_in  = (const float*)d_in[8];
  const float* ib_in  = (const float*)d_in[9];
  const float* iW_hid = (const float*)d_in[10];
  const float* ib_hid = (const float*)d_in[11];
  const float* iW_out = (const float*)d_in[12];
  const float* ib_out = (const float*)d_in[13];
  float* out = (float*)d_out;

  // ws layout (u16 hi/lo stage buffers, stride 33):
  //  A: 524288 rows, B: 262144 rows; levels ping-pong A<->B.
  const size_t rowsA = (size_t)Bn * LEAVES;       // 524288
  const size_t rowsB = rowsA / 2;                 // 262144
  unsigned short* AH = (unsigned short*)d_ws;
  unsigned short* AL = AH + rowsA * 33;
  unsigned short* BH = AL + rowsA * 33;
  unsigned short* BL = BH + rowsB * 33;
  unsigned short* warena = BL + rowsB * 33;
  float* barena = (float*)(warena + 24 * MATSZ);  // total ~104.7 MB

  prep_kernel<<<dim3((MATSZ + THREADS - 1) / THREADS, 12), THREADS, 0, stream>>>(
      lW_in, lW_hid, lW_out, lb_in, lb_hid, lb_out,
      iW_in, iW_hid, iW_out, ib_in, ib_hid, ib_out, warena, barena);

  leaf_kernel<<<(Bn * LEAVES) / 64, THREADS, 0, stream>>>(leaf_feat, warena, barena, AH, AL);

  // All 10 interior levels batched across batches; 64 real rows per block.
  // d:     9     8     7     6     5    4    3    2    1    0
  // grid: 4096  2048  1024  512   256  128  64   32   16   8
  int_kernel<<<4096, THREADS, 0, stream>>>(int_feat, AH, AL, warena, barena, BH, BL, nullptr, 512, 9);
  int_kernel<<<2048, THREADS, 0, stream>>>(int_feat, BH, BL, warena, barena, AH, AL, nullptr, 256, 8);
  int_kernel<<<1024, THREADS, 0, stream>>>(int_feat, AH, AL, warena, barena, BH, BL, nullptr, 128, 7);
  int_kernel<<< 512, THREADS, 0, stream>>>(int_feat, BH, BL, warena, barena, AH, AL, nullptr,  64, 6);
  int_kernel<<< 256, THREADS, 0, stream>>>(int_feat, AH, AL, warena, barena, BH, BL, nullptr,  32, 5);
  int_kernel<<< 128, THREADS, 0, stream>>>(int_feat, BH, BL, warena, barena, AH, AL, nullptr,  16, 4);
  int_kernel<<<  64, THREADS, 0, stream>>>(int_feat, AH, AL, warena, barena, BH, BL, nullptr,   8, 3);
  int_kernel<<<  32, THREADS, 0, stream>>>(int_feat, BH, BL, warena, barena, AH, AL, nullptr,   4, 2);
  int_kernel<<<  16, THREADS, 0, stream>>>(int_feat, AH, AL, warena, barena, BH, BL, nullptr,   2, 1);
  int_kernel<<<   8, THREADS, 0, stream>>>(int_feat, BH, BL, warena, barena, AH, AL, out,        1, 0);
}